// Round 4
// baseline (174.575 us; speedup 1.0000x reference)
//
#include <hip/hip_runtime.h>
#include <math.h>

#define TB 2
#define TT 2048
#define NH 16
#define HD 64
#define HSZ 1024
#define NROW 65536          // B*T*NH q-rows
#define OPHALF 4194304      // NROW * HD

typedef float floatx4 __attribute__((ext_vector_type(4)));
typedef __bf16 bf16x4 __attribute__((ext_vector_type(4)));
typedef __bf16 bf16x8 __attribute__((ext_vector_type(8)));

#define LOG2E  1.4426950408889634f
#define NEGF   (-0.4152410118609203f)   // -log2(10000)/32
#define INV2PI 0.15915494309189535f

// ============ phase 1: fused prep — RoPE-K pack + V transpose-pack ============
__global__ __launch_bounds__(256)
void prep_kernel(const float* __restrict__ K, const float* __restrict__ V,
                 __bf16* __restrict__ Kp, __bf16* __restrict__ Vp) {
    int blk = blockIdx.x;               // bh*32 + kt, 1024 blocks
    int kt = blk & 31;
    int bh = blk >> 5;
    int b = bh >> 4, h = bh & 15;
    int tid = threadIdx.x;

    // ---- K part: thread -> (key=tid>>2, dim-octet qq=tid&3) ----
    // Kp layout: subtile nt=key&3, column key>>2 -> logical k = 4*col + nt.
    {
        int key = tid >> 2, qq = tid & 3;
        int tglob = kt * 64 + key;
        const float* krow = K + ((size_t)(b * TT + tglob)) * HSZ + h * HD + qq * 8;
        float x0[8], x1[8];
        *(floatx4*)&x0[0] = *(const floatx4*)&krow[0];
        *(floatx4*)&x0[4] = *(const floatx4*)&krow[4];
        *(floatx4*)&x1[0] = *(const floatx4*)&krow[32];
        *(floatx4*)&x1[4] = *(const floatx4*)&krow[36];
        bf16x8 y0, y1;
        #pragma unroll
        for (int j = 0; j < 8; ++j) {
            float freq = exp2f((float)(qq * 8 + j) * NEGF);
            float rv = (float)tglob * freq * INV2PI;
            rv -= floorf(rv);
            float s = __builtin_amdgcn_sinf(rv);
            float c = __builtin_amdgcn_cosf(rv);
            y0[j] = (__bf16)(x0[j] * c - x1[j] * s);
            y1[j] = (__bf16)(x1[j] * c + x0[j] * s);
        }
        size_t base = ((size_t)blk * 4 + (key & 3)) * 1024 + (size_t)(qq * 16 + (key >> 2)) * 8;
        *(bf16x8*)(Kp + base)       = y0;
        *(bf16x8*)(Kp + base + 512) = y1;
    }

    // ---- V part: transpose 64x64 via LDS ----
    __shared__ __bf16 lt[64][72];
    {
        int vkey = tid >> 2, dg = (tid & 3) * 16;
        const float* vrow = V + ((size_t)(b * TT + kt * 64 + vkey)) * HSZ + h * HD + dg;
        floatx4 v0 = *(const floatx4*)&vrow[0];
        floatx4 v1 = *(const floatx4*)&vrow[4];
        floatx4 v2 = *(const floatx4*)&vrow[8];
        floatx4 v3 = *(const floatx4*)&vrow[12];
        #pragma unroll
        for (int j = 0; j < 4; ++j) {
            lt[dg + j][vkey]      = (__bf16)v0[j];
            lt[dg + 4 + j][vkey]  = (__bf16)v1[j];
            lt[dg + 8 + j][vkey]  = (__bf16)v2[j];
            lt[dg + 12 + j][vkey] = (__bf16)v3[j];
        }
    }
    __syncthreads();
    // Vp layout for in-register PV (swapped-QK^T): B-fragment (g, dn), lane l,
    // element e must hold V[k = (l>>4)*16 + g*8 + e][d = dn*16 + (l&15)].
    #pragma unroll
    for (int ss = 0; ss < 2; ++ss) {
        int sidx = tid + ss * 256;
        int hg = sidx >> 6;             // hg = g*4 + dn
        int l = sidx & 63;
        int g = hg >> 2, dn = hg & 3;
        int lq = l >> 4, lr = l & 15;
        bf16x8 o = *(const bf16x8*)&lt[dn * 16 + lr][lq * 16 + g * 8];
        *(bf16x8*)(Vp + (size_t)blk * 4096 + (size_t)hg * 512 + (size_t)l * 8) = o;
    }
}

// ============ phase 2: split-K flash attention, 32 q-rows per wave ============
// Swapped QK^T (P fully in-register) + explicit software pipeline:
//   - bv double-buffered in registers (bvA/bvB, kt unrolled by 2, static names)
//   - load clusters pinned with sched_barrier(0) so the compiler cannot sink
//     them to their uses (VGPR=88 in round 3 proved it was doing exactly that,
//     exposing full L2 latency inside every iteration)
//   - s_setprio(1) around MFMA clusters (T5) to de-phase co-resident waves
__global__ __launch_bounds__(256, 2)
void attn_kernel(const float* __restrict__ Q, const __bf16* __restrict__ Kp,
                 const __bf16* __restrict__ Vp, __bf16* __restrict__ Op,
                 float* __restrict__ lp) {
    // bijective XCD swizzle (1024 % 8 == 0): same-bh blocks share an XCD L2.
    int blk0 = blockIdx.x;
    int blk = (blk0 & 7) * 128 + (blk0 >> 3);

    int s = blk & 1;
    int qb = (blk >> 1) & 15;           // 16 q-blocks of 128 rows
    int bh = blk >> 5;
    int b = bh >> 4, h = bh & 15;
    int tid = threadIdx.x;
    int wave = tid >> 6, lane = tid & 63;
    int lane15 = lane & 15, quad = lane >> 4;

    const float scale2 = 0.125f * LOG2E;
    const float slope2 = exp2f(-0.5f * (float)(h + 1)) * LOG2E;
    const float ms     = slope2 * 2047.0f + 20.0f;      // static log2-domain shift

    // ---- Q load + RoPE into 2 B-fragment pairs (32 q-rows/wave) ----
    int qbase = qb * 128 + wave * 32;
    int d0 = quad * 8;
    bf16x8 aQ0[2], aQ1[2];
    #pragma unroll
    for (int qf = 0; qf < 2; ++qf) {
        int t_q = qbase + qf * 16 + lane15;
        const float* qrow = Q + ((size_t)(b * TT + t_q) * HSZ) + h * HD;
        float q0[8], q1[8];
        *(floatx4*)&q0[0] = *(const floatx4*)&qrow[d0];
        *(floatx4*)&q0[4] = *(const floatx4*)&qrow[d0 + 4];
        *(floatx4*)&q1[0] = *(const floatx4*)&qrow[d0 + 32];
        *(floatx4*)&q1[4] = *(const floatx4*)&qrow[d0 + 36];
        #pragma unroll
        for (int j = 0; j < 8; ++j) {
            float freq = exp2f((float)(d0 + j) * NEGF);
            float rv = (float)t_q * freq * INV2PI;
            rv -= floorf(rv);
            float sn = __builtin_amdgcn_sinf(rv);
            float cs = __builtin_amdgcn_cosf(rv);
            aQ0[qf][j] = (__bf16)((q0[j] * cs - q1[j] * sn) * scale2);
            aQ1[qf][j] = (__bf16)((q1[j] * cs + q0[j] * sn) * scale2);
        }
    }

    const float qb16  = slope2 * (float)(16 * quad) - ms;
    const float dstep = slope2 * 64.0f;

    floatx4 O[2][4];
    float lrow[2];
    #pragma unroll
    for (int qf = 0; qf < 2; ++qf) {
        lrow[qf] = 0.f;
        #pragma unroll
        for (int r = 0; r < 4; ++r)
            O[qf][r] = (floatx4){0.f, 0.f, 0.f, 0.f};
    }

    const __bf16* Kb = Kp + (size_t)bh * (TT * HD) + (size_t)lane * 8;
    const __bf16* Vb = Vp + (size_t)bh * (TT * HD) + (size_t)lane * 8;

    const int kt0 = s * 16, kt1 = s * 16 + 16;

    bf16x8 bk[4][2];
    bf16x8 bvA[2][4], bvB[2][4];

    // QK^T for one q-fragment (swapped operands: mfma(K, Q) -> P^T)
    auto qk = [&](floatx4 (&acc)[4], bf16x8& aq0, bf16x8& aq1) {
        __builtin_amdgcn_s_setprio(1);
        #pragma unroll
        for (int nt = 0; nt < 4; ++nt) {
            floatx4 a = {0.f, 0.f, 0.f, 0.f};
            a = __builtin_amdgcn_mfma_f32_16x16x32_bf16(bk[nt][0], aq0, a, 0, 0, 0);
            a = __builtin_amdgcn_mfma_f32_16x16x32_bf16(bk[nt][1], aq1, a, 0, 0, 0);
            acc[nt] = a;
        }
        __builtin_amdgcn_s_setprio(0);
    };

    // softmax + PV for one q-fragment (refs avoid runtime array indexing)
    auto softmax_pv = [&](floatx4 (&acc)[4], bf16x8 (&bvt)[2][4],
                          float& lq, floatx4 (&Oq)[4], float biasq) {
        #pragma unroll
        for (int g = 0; g < 2; ++g) {
            float p[8];
            #pragma unroll
            for (int j = 0; j < 8; ++j) {
                int nt = j & 3, r = g * 2 + (j >> 2);
                p[j] = __builtin_amdgcn_exp2f(
                    acc[nt][r] + fmaf(slope2, (float)(4 * r + nt), biasq));
            }
            lq += ((p[0] + p[1]) + (p[2] + p[3])) + ((p[4] + p[5]) + (p[6] + p[7]));
            bf16x8 aP;
            #pragma unroll
            for (int j = 0; j < 8; ++j) aP[j] = (__bf16)p[j];
            __builtin_amdgcn_s_setprio(1);
            Oq[0] = __builtin_amdgcn_mfma_f32_16x16x32_bf16(aP, bvt[g][0], Oq[0], 0, 0, 0);
            Oq[1] = __builtin_amdgcn_mfma_f32_16x16x32_bf16(aP, bvt[g][1], Oq[1], 0, 0, 0);
            Oq[2] = __builtin_amdgcn_mfma_f32_16x16x32_bf16(aP, bvt[g][2], Oq[2], 0, 0, 0);
            Oq[3] = __builtin_amdgcn_mfma_f32_16x16x32_bf16(aP, bvt[g][3], Oq[3], 0, 0, 0);
            __builtin_amdgcn_s_setprio(0);
        }
    };

    auto load_bv = [&](bf16x8 (&bvt)[2][4], int kt_) {
        const __bf16* vb = Vb + (size_t)kt_ * 4096;
        #pragma unroll
        for (int hg = 0; hg < 8; ++hg)
            bvt[hg >> 2][hg & 3] = *(const bf16x8*)(vb + hg * 512);
    };
    auto load_bk = [&](int kt_) {
        const __bf16* kb = Kb + (size_t)kt_ * 4096;
        #pragma unroll
        for (int nt = 0; nt < 4; ++nt) {
            bk[nt][0] = *(const bf16x8*)(kb + nt * 1024);
            bk[nt][1] = *(const bf16x8*)(kb + nt * 1024 + 512);
        }
    };

    // prologue: current tile's K and V
    load_bk(kt0);
    load_bv(bvA, kt0);

    #pragma unroll 1
    for (int kt = kt0; kt < kt1; kt += 2) {
        // ---------- step A: consume bvA (tile kt), prefetch bvB (kt+1) ----------
        {
            load_bv(bvB, kt + 1);                    // issue early…
            __builtin_amdgcn_sched_barrier(0);       // …and pin here
            float biasq = qb16 + dstep * (float)kt;
            floatx4 acc[4];
            qk(acc, aQ0[0], aQ1[0]);
            softmax_pv(acc, bvA, lrow[0], O[0], biasq);
            qk(acc, aQ0[1], aQ1[1]);
            load_bk(kt + 1);                         // bk free after both QKs
            __builtin_amdgcn_sched_barrier(0);       // pin: don't sink to tail
            softmax_pv(acc, bvA, lrow[1], O[1], biasq);
        }
        // ---------- step B: consume bvB (tile kt+1), prefetch bvA (kt+2) ----------
        {
            int kt2 = kt + 2; if (kt2 >= kt1) kt2 = kt0;   // uniform, in-bounds
            load_bv(bvA, kt2);
            __builtin_amdgcn_sched_barrier(0);
            float biasq = qb16 + dstep * (float)(kt + 1);
            floatx4 acc[4];
            qk(acc, aQ0[0], aQ1[0]);
            softmax_pv(acc, bvB, lrow[0], O[0], biasq);
            qk(acc, aQ0[1], aQ1[1]);
            load_bk(kt2);
            __builtin_amdgcn_sched_barrier(0);
            softmax_pv(acc, bvB, lrow[1], O[1], biasq);
        }
    }

    // ---- epilogue: reduce l across quads, store bf16 partial O + fp32 l ----
    #pragma unroll
    for (int qf = 0; qf < 2; ++qf) {
        float l = lrow[qf];
        l += __shfl_xor(l, 16);
        l += __shfl_xor(l, 32);
        int q0 = qbase + qf * 16;
        if (quad == 0) {
            int ridl = (b * TT + q0 + lane15) * NH + h;
            lp[s * NROW + ridl] = l;
        }
        #pragma unroll
        for (int r = 0; r < 4; ++r) {
            int rid = (b * TT + q0 + quad * 4 + r) * NH + h;
            size_t base = ((size_t)s * NROW + rid) * HD + lane15;
            Op[base +  0] = (__bf16)O[qf][0][r];
            Op[base + 16] = (__bf16)O[qf][1][r];
            Op[base + 32] = (__bf16)O[qf][2][r];
            Op[base + 48] = (__bf16)O[qf][3][r];
        }
    }
}

// ============ phase 3: combine splits ============
__global__ __launch_bounds__(256)
void reduce_kernel(const __bf16* __restrict__ Op, const float* __restrict__ lp,
                   float* __restrict__ Out) {
    int i = blockIdx.x * 256 + threadIdx.x;    // 1048576 threads, one float4 each
    size_t f = (size_t)i * 4;
    int rid = (int)(f >> 6);
    bf16x4 a = *(const bf16x4*)(Op + f);
    bf16x4 c = *(const bf16x4*)(Op + OPHALF + f);
    float inv = 1.0f / (lp[rid] + lp[NROW + rid]);
    floatx4 o;
    #pragma unroll
    for (int j = 0; j < 4; ++j)
        o[j] = ((float)a[j] + (float)c[j]) * inv;
    *(floatx4*)(Out + f) = o;
}

extern "C" void kernel_launch(void* const* d_in, const int* in_sizes, int n_in,
                              void* d_out, int out_size, void* d_ws, size_t ws_size,
                              hipStream_t stream) {
    const float* q = (const float*)d_in[0];
    const float* k = (const float*)d_in[1];
    const float* v = (const float*)d_in[2];
    float* out = (float*)d_out;

    char* ws = (char*)d_ws;
    __bf16* Kp = (__bf16*)ws;                                  // 8 MB
    __bf16* Vp = (__bf16*)(ws + (size_t)8 * 1024 * 1024);      // 8 MB
    __bf16* Op = (__bf16*)(ws + (size_t)16 * 1024 * 1024);     // 16 MB (2 splits bf16)
    float*  lp = (float*)(ws + (size_t)33 * 1024 * 1024);      // 512 KB

    prep_kernel<<<dim3(TB * NH * (TT / 64)), 256, 0, stream>>>(k, v, Kp, Vp);
    attn_kernel<<<dim3(TB * NH * 32), 256, 0, stream>>>(q, Kp, Vp, Op, lp);
    reduce_kernel<<<dim3((TB * TT * HSZ / 4) / 256), 256, 0, stream>>>(Op, lp, out);
}

// Round 5
// 136.916 us; speedup vs baseline: 1.2751x; 1.2751x over previous
//
#include <hip/hip_runtime.h>
#include <math.h>

#define TB 2
#define TT 2048
#define NH 16
#define HD 64
#define HSZ 1024

typedef float floatx4 __attribute__((ext_vector_type(4)));
typedef __bf16 bf16x4 __attribute__((ext_vector_type(4)));
typedef __bf16 bf16x8 __attribute__((ext_vector_type(8)));

#define LOG2E  1.4426950408889634f
#define NEGF   (-0.4152410118609203f)   // -log2(10000)/32
#define INV2PI 0.15915494309189535f

// ============ phase 1: fused prep — RoPE-K pack + V transpose-pack ============
__global__ __launch_bounds__(256)
void prep_kernel(const float* __restrict__ K, const float* __restrict__ V,
                 __bf16* __restrict__ Kp, __bf16* __restrict__ Vp) {
    int blk = blockIdx.x;               // bh*32 + kt, 1024 blocks
    int kt = blk & 31;
    int bh = blk >> 5;
    int b = bh >> 4, h = bh & 15;
    int tid = threadIdx.x;

    // ---- K part: thread -> (key=tid>>2, dim-octet qq=tid&3) ----
    {
        int key = tid >> 2, qq = tid & 3;
        int tglob = kt * 64 + key;
        const float* krow = K + ((size_t)(b * TT + tglob)) * HSZ + h * HD + qq * 8;
        float x0[8], x1[8];
        *(floatx4*)&x0[0] = *(const floatx4*)&krow[0];
        *(floatx4*)&x0[4] = *(const floatx4*)&krow[4];
        *(floatx4*)&x1[0] = *(const floatx4*)&krow[32];
        *(floatx4*)&x1[4] = *(const floatx4*)&krow[36];
        bf16x8 y0, y1;
        #pragma unroll
        for (int j = 0; j < 8; ++j) {
            float freq = exp2f((float)(qq * 8 + j) * NEGF);
            float rv = (float)tglob * freq * INV2PI;
            rv -= floorf(rv);
            float s = __builtin_amdgcn_sinf(rv);
            float c = __builtin_amdgcn_cosf(rv);
            y0[j] = (__bf16)(x0[j] * c - x1[j] * s);
            y1[j] = (__bf16)(x1[j] * c + x0[j] * s);
        }
        size_t base = ((size_t)blk * 4 + (key & 3)) * 1024 + (size_t)(qq * 16 + (key >> 2)) * 8;
        *(bf16x8*)(Kp + base)       = y0;
        *(bf16x8*)(Kp + base + 512) = y1;
    }

    // ---- V part: transpose 64x64 via LDS ----
    __shared__ __bf16 lt[64][72];
    {
        int vkey = tid >> 2, dg = (tid & 3) * 16;
        const float* vrow = V + ((size_t)(b * TT + kt * 64 + vkey)) * HSZ + h * HD + dg;
        floatx4 v0 = *(const floatx4*)&vrow[0];
        floatx4 v1 = *(const floatx4*)&vrow[4];
        floatx4 v2 = *(const floatx4*)&vrow[8];
        floatx4 v3 = *(const floatx4*)&vrow[12];
        #pragma unroll
        for (int j = 0; j < 4; ++j) {
            lt[dg + j][vkey]      = (__bf16)v0[j];
            lt[dg + 4 + j][vkey]  = (__bf16)v1[j];
            lt[dg + 8 + j][vkey]  = (__bf16)v2[j];
            lt[dg + 12 + j][vkey] = (__bf16)v3[j];
        }
    }
    __syncthreads();
    #pragma unroll
    for (int ss = 0; ss < 2; ++ss) {
        int s = tid + ss * 256;
        int hg = s >> 6;
        int l = s & 63;
        int lq = l >> 4, lr = l & 15;
        int h2 = hg >> 2, g = hg & 3;
        bf16x8 o = *(const bf16x8*)&lt[g * 16 + lr][h2 * 32 + lq * 8];
        *(bf16x8*)(Vp + (size_t)blk * 4096 + (size_t)hg * 512 + (size_t)l * 8) = o;
    }
}

// ============ phase 2: flash attention, NO split-K, 32 q-rows per wave ============
// Round-2 inner loop (best measured 56.0 us) extended to the full 32 kt tiles.
// Split-K removed: the Op/lp round-trip + reduce_kernel accounted for most of
// the ~85us constant non-attn time (prep+reduce roofline is ~16us). Epilogue
// normalizes in-register and writes fp32 Out directly.
__global__ __launch_bounds__(256, 2)
void attn_kernel(const float* __restrict__ Q, const __bf16* __restrict__ Kp,
                 const __bf16* __restrict__ Vp, float* __restrict__ Out) {
    // bijective XCD swizzle (512 % 8 == 0): 64 consecutive work-ids per XCD
    // -> same-bh blocks share the XCD's L2 (Kp+Vp working set 1 MB/bh).
    int blk0 = blockIdx.x;
    int blk = (blk0 & 7) * 64 + (blk0 >> 3);

    int qb = blk & 15;                  // 16 q-blocks of 128 rows
    int bh = blk >> 4;
    int b = bh >> 4, h = bh & 15;
    int tid = threadIdx.x;
    int wave = tid >> 6, lane = tid & 63;
    int lane15 = lane & 15, quad = lane >> 4;

    // per-wave, per-qf P round-trip tiles; no __syncthreads anywhere
    __shared__ __align__(16) __bf16 sP[4][2][16][72];   // 18432 B

    const float scale2 = 0.125f * LOG2E;
    const float slope2 = exp2f(-0.5f * (float)(h + 1)) * LOG2E;
    const float ms     = slope2 * 2047.0f + 20.0f;      // static log2-domain shift

    // ---- Q load + RoPE into 2 A-fragment pairs (32 q-rows/wave) ----
    int qbase = qb * 128 + wave * 32;
    int d0 = quad * 8;
    bf16x8 aQ0[2], aQ1[2];
    #pragma unroll
    for (int qf = 0; qf < 2; ++qf) {
        int t_q = qbase + qf * 16 + lane15;
        const float* qrow = Q + ((size_t)(b * TT + t_q) * HSZ) + h * HD;
        float q0[8], q1[8];
        *(floatx4*)&q0[0] = *(const floatx4*)&qrow[d0];
        *(floatx4*)&q0[4] = *(const floatx4*)&qrow[d0 + 4];
        *(floatx4*)&q1[0] = *(const floatx4*)&qrow[d0 + 32];
        *(floatx4*)&q1[4] = *(const floatx4*)&qrow[d0 + 36];
        #pragma unroll
        for (int j = 0; j < 8; ++j) {
            float freq = exp2f((float)(d0 + j) * NEGF);
            float rv = (float)t_q * freq * INV2PI;
            rv -= floorf(rv);
            float sn = __builtin_amdgcn_sinf(rv);
            float cs = __builtin_amdgcn_cosf(rv);
            aQ0[qf][j] = (__bf16)((q0[j] * cs - q1[j] * sn) * scale2);
            aQ1[qf][j] = (__bf16)((q1[j] * cs + q0[j] * sn) * scale2);
        }
    }

    float slk2[4];
    #pragma unroll
    for (int nt = 0; nt < 4; ++nt)
        slk2[nt] = slope2 * (float)(4 * lane15 + nt) - ms;
    const float dstep = slope2 * 64.0f;

    floatx4 O[2][4];
    float lrow[2][4];
    #pragma unroll
    for (int qf = 0; qf < 2; ++qf)
        #pragma unroll
        for (int r = 0; r < 4; ++r) {
            O[qf][r] = (floatx4){0.f, 0.f, 0.f, 0.f};
            lrow[qf][r] = 0.f;
        }

    const __bf16* Kb = Kp + (size_t)bh * (TT * HD) + (size_t)lane * 8;
    const __bf16* Vb = Vp + (size_t)bh * (TT * HD) + (size_t)lane * 8;

    const int kt1 = TT / 64;            // 32 tiles, full sequence

    // prologue: K fragments for first tile
    bf16x8 bk[4][2];
    {
        const __bf16* kbase = Kb;
        #pragma unroll
        for (int nt = 0; nt < 4; ++nt) {
            bk[nt][0] = *(const bf16x8*)(kbase + nt * 1024);
            bk[nt][1] = *(const bf16x8*)(kbase + nt * 1024 + 512);
        }
    }

    #pragma unroll 1
    for (int kt = 0; kt < kt1; ++kt) {
        // ---- V fragments for this tile (consumed in phase 2: latency hidden) ----
        const __bf16* vbase = Vb + (size_t)kt * 4096;
        bf16x8 bv[2][4];
        #pragma unroll
        for (int hg = 0; hg < 8; ++hg)
            bv[hg >> 2][hg & 3] = *(const bf16x8*)(vbase + hg * 512);

        // ---- phase 1: QK^T + exp2 + sP, for both q-fragments ----
        float biask = dstep * (float)kt;
        #pragma unroll
        for (int qf = 0; qf < 2; ++qf) {
            float P[4][4];
            #pragma unroll
            for (int nt = 0; nt < 4; ++nt) {
                floatx4 acc = {0.f, 0.f, 0.f, 0.f};
                acc = __builtin_amdgcn_mfma_f32_16x16x32_bf16(aQ0[qf], bk[nt][0], acc, 0, 0, 0);
                acc = __builtin_amdgcn_mfma_f32_16x16x32_bf16(aQ1[qf], bk[nt][1], acc, 0, 0, 0);
                float bias = slk2[nt] + biask;
                #pragma unroll
                for (int r = 0; r < 4; ++r)
                    P[nt][r] = __builtin_amdgcn_exp2f(acc[r] + bias);
            }
            #pragma unroll
            for (int r = 0; r < 4; ++r) {
                lrow[qf][r] += (P[0][r] + P[1][r]) + (P[2][r] + P[3][r]);
                bf16x4 pp;
                pp[0] = (__bf16)P[0][r]; pp[1] = (__bf16)P[1][r];
                pp[2] = (__bf16)P[2][r]; pp[3] = (__bf16)P[3][r];
                *(bf16x4*)&sP[wave][qf][quad * 4 + r][4 * lane15] = pp;
            }
        }

        // ---- prefetch K fragments for next tile (hidden under phase 2) ----
        if (kt + 1 < kt1) {
            const __bf16* kbase = Kb + (size_t)(kt + 1) * 4096;
            #pragma unroll
            for (int nt = 0; nt < 4; ++nt) {
                bk[nt][0] = *(const bf16x8*)(kbase + nt * 1024);
                bk[nt][1] = *(const bf16x8*)(kbase + nt * 1024 + 512);
            }
        }

        // ---- phase 2: PV for both q-fragments ----
        #pragma unroll
        for (int qf = 0; qf < 2; ++qf) {
            #pragma unroll
            for (int h2 = 0; h2 < 2; ++h2) {
                bf16x8 aP = *(const bf16x8*)&sP[wave][qf][lane15][h2 * 32 + quad * 8];
                O[qf][0] = __builtin_amdgcn_mfma_f32_16x16x32_bf16(aP, bv[h2][0], O[qf][0], 0, 0, 0);
                O[qf][1] = __builtin_amdgcn_mfma_f32_16x16x32_bf16(aP, bv[h2][1], O[qf][1], 0, 0, 0);
                O[qf][2] = __builtin_amdgcn_mfma_f32_16x16x32_bf16(aP, bv[h2][2], O[qf][2], 0, 0, 0);
                O[qf][3] = __builtin_amdgcn_mfma_f32_16x16x32_bf16(aP, bv[h2][3], O[qf][3], 0, 0, 0);
            }
        }
    }

    // ---- epilogue: reduce l, normalize in-register, write fp32 Out directly ----
    #pragma unroll
    for (int qf = 0; qf < 2; ++qf) {
        #pragma unroll
        for (int r = 0; r < 4; ++r) {
            float l = lrow[qf][r];
            l += __shfl_xor(l, 1);
            l += __shfl_xor(l, 2);
            l += __shfl_xor(l, 4);
            l += __shfl_xor(l, 8);
            float inv = 1.0f / l;
            int t = qbase + qf * 16 + quad * 4 + r;
            size_t base = ((size_t)(b * TT + t)) * HSZ + h * HD + lane15;
            Out[base +  0] = O[qf][0][r] * inv;
            Out[base + 16] = O[qf][1][r] * inv;
            Out[base + 32] = O[qf][2][r] * inv;
            Out[base + 48] = O[qf][3][r] * inv;
        }
    }
}

extern "C" void kernel_launch(void* const* d_in, const int* in_sizes, int n_in,
                              void* d_out, int out_size, void* d_ws, size_t ws_size,
                              hipStream_t stream) {
    const float* q = (const float*)d_in[0];
    const float* k = (const float*)d_in[1];
    const float* v = (const float*)d_in[2];
    float* out = (float*)d_out;

    char* ws = (char*)d_ws;
    __bf16* Kp = (__bf16*)ws;                                  // 8 MB
    __bf16* Vp = (__bf16*)(ws + (size_t)8 * 1024 * 1024);      // 8 MB

    prep_kernel<<<dim3(TB * NH * (TT / 64)), 256, 0, stream>>>(k, v, Kp, Vp);
    attn_kernel<<<dim3(TB * NH * 16), 256, 0, stream>>>(q, Kp, Vp, out);
}